// Round 2
// baseline (925.450 us; speedup 1.0000x reference)
//
#include <hip/hip_runtime.h>
#include <hip/hip_bf16.h>

#define B_ROWS 256
#define S_SUP  65536
#define D_DIM  768
#define QSZ    512

typedef short bf16x8 __attribute__((ext_vector_type(8)));
typedef float f32x4  __attribute__((ext_vector_type(4)));

__device__ __forceinline__ bf16x8 cvt8(float4 a, float4 b) {
  bf16x8 r;
  r[0] = (short)(__float_as_uint(a.x) >> 16);
  r[1] = (short)(__float_as_uint(a.y) >> 16);
  r[2] = (short)(__float_as_uint(a.z) >> 16);
  r[3] = (short)(__float_as_uint(a.w) >> 16);
  r[4] = (short)(__float_as_uint(b.x) >> 16);
  r[5] = (short)(__float_as_uint(b.y) >> 16);
  r[6] = (short)(__float_as_uint(b.z) >> 16);
  r[7] = (short)(__float_as_uint(b.w) >> 16);
  return r;
}

// block-wide sum (float), result broadcast to all 256 threads (4 waves)
__device__ __forceinline__ float block_sum(float v) {
  __shared__ float tmp[4];
  #pragma unroll
  for (int m = 32; m >= 1; m >>= 1) v += __shfl_xor(v, m, 64);
  __syncthreads();
  if ((threadIdx.x & 63) == 0) tmp[threadIdx.x >> 6] = v;
  __syncthreads();
  return tmp[0] + tmp[1] + tmp[2] + tmp[3];
}

// block-wide sum (double), result broadcast
__device__ __forceinline__ double block_sum_d(double v) {
  __shared__ double tmp[4];
  #pragma unroll
  for (int m = 32; m >= 1; m >>= 1) v += __shfl_xor(v, m, 64);
  __syncthreads();
  if ((threadIdx.x & 63) == 0) tmp[threadIdx.x >> 6] = v;
  __syncthreads();
  return tmp[0] + tmp[1] + tmp[2] + tmp[3];
}

// ---- kernel 0: zero accumulators (ws is poisoned 0xAA before every call) ----
__global__ __launch_bounds__(256) void init_kernel(unsigned long long* gmax, double* bden) {
  int t = threadIdx.x;
  gmax[t] = 0ull;
  for (int i = t; i < 3 * B_ROWS; i += 256) bden[i] = 0.0;
}

// ---- kernel 1: org = normalize(V[0]*L); augs[j-1] = normalize(V[j]*L) ----
__global__ __launch_bounds__(256) void prep_kernel(const float* __restrict__ V,
                                                   const float* __restrict__ L,
                                                   float* __restrict__ org,
                                                   float* __restrict__ augs) {
  int jb = blockIdx.x;            // 0..1023
  int j = jb >> 8, b = jb & 255;
  int tid = threadIdx.x;
  const float* v = V + ((size_t)j * B_ROWS + b) * D_DIM;
  const float* l = L + (size_t)b * D_DIM;
  float p[3]; float ssq = 0.f;
  #pragma unroll
  for (int i = 0; i < 3; ++i) {
    int k = tid + 256 * i;
    p[i] = v[k] * l[k];
    ssq += p[i] * p[i];
  }
  ssq = block_sum(ssq);
  float inv = 1.0f / fmaxf(sqrtf(ssq), 1e-12f);
  float* dst = (j == 0) ? (org + (size_t)b * D_DIM)
                        : (augs + ((size_t)(j - 1) * B_ROWS + b) * D_DIM);
  #pragma unroll
  for (int i = 0; i < 3; ++i) dst[tid + 256 * i] = p[i] * inv;
}

// ---- kernel 2: sim = org @ sf^T (bf16 MFMA), per-row argmax via packed atomicMax ----
__global__ __launch_bounds__(256) void sim_argmax_kernel(const float* __restrict__ org,
                                                         const float* __restrict__ sf,
                                                         unsigned long long* __restrict__ gmax) {
  const int tid  = threadIdx.x;
  const int w    = tid >> 6;          // wave 0..3
  const int lid  = tid & 63;
  const int quad = lid >> 4;          // 0..3
  const int r15  = lid & 15;          // 0..15
  const int s_col = blockIdx.x * 64 + w * 16 + r15;

  f32x4 acc[16];
  #pragma unroll
  for (int t = 0; t < 16; ++t) acc[t] = (f32x4){0.f, 0.f, 0.f, 0.f};

  const float* bp = sf + (size_t)s_col * D_DIM + quad * 8;
  for (int k0 = 0; k0 < D_DIM; k0 += 32) {
    float4 b0 = *(const float4*)(bp + k0);
    float4 b1 = *(const float4*)(bp + k0 + 4);
    bf16x8 bf = cvt8(b0, b1);
    const float* ap = org + (size_t)r15 * D_DIM + k0 + quad * 8;
    #pragma unroll
    for (int t = 0; t < 16; ++t) {
      float4 a0 = *(const float4*)(ap);
      float4 a1 = *(const float4*)(ap + 4);
      ap += 16 * D_DIM;
      bf16x8 af = cvt8(a0, a1);
      acc[t] = __builtin_amdgcn_mfma_f32_16x16x32_bf16(af, bf, acc[t], 0, 0, 0);
    }
  }

  __shared__ float smax[4 * 256];
  __shared__ int   sidx[4 * 256];
  #pragma unroll
  for (int t = 0; t < 16; ++t) {
    #pragma unroll
    for (int r = 0; r < 4; ++r) {
      float v = acc[t][r];
      int   idx = s_col;
      #pragma unroll
      for (int m = 1; m < 16; m <<= 1) {     // reduce over the 16 lanes sharing a quad
        float ov = __shfl_xor(v, m, 64);
        int   oi = __shfl_xor(idx, m, 64);
        if (ov > v || (ov == v && oi < idx)) { v = ov; idx = oi; }
      }
      if (r15 == 0) {
        int b = 16 * t + 4 * quad + r;       // C/D layout: row = quad*4+reg
        smax[w * 256 + b] = v;
        sidx[w * 256 + b] = idx;
      }
    }
  }
  __syncthreads();
  {
    int b = tid;
    float v = smax[b]; int idx = sidx[b];
    #pragma unroll
    for (int w2 = 1; w2 < 4; ++w2) {
      float ov = smax[w2 * 256 + b]; int oi = sidx[w2 * 256 + b];
      if (ov > v || (ov == v && oi < idx)) { v = ov; idx = oi; }
    }
    unsigned u = __float_as_uint(v);
    unsigned key = (u & 0x80000000u) ? ~u : (u | 0x80000000u);
    unsigned long long packed = ((unsigned long long)key << 32) |
                                (unsigned long long)(0xFFFFFFFFu - (unsigned)idx);
    atomicMax(gmax + b, packed);
  }
}

// ---- kernel 3: nn = normalize(sf[nn_idx]); nnT; num = dot(nn, augs[0][b]) / T ----
__global__ __launch_bounds__(256) void nn_kernel(const unsigned long long* __restrict__ gmax,
                                                 const float* __restrict__ sf,
                                                 const float* __restrict__ augs,
                                                 float* __restrict__ nn,
                                                 float* __restrict__ nnT,
                                                 float* __restrict__ num) {
  int b = blockIdx.x, tid = threadIdx.x;
  int idx = (int)(0xFFFFFFFFu - (unsigned)(gmax[b] & 0xFFFFFFFFull));
  const float* row = sf + (size_t)idx * D_DIM;
  float p[3]; float ssq = 0.f;
  #pragma unroll
  for (int i = 0; i < 3; ++i) { p[i] = row[tid + 256 * i]; ssq += p[i] * p[i]; }
  ssq = block_sum(ssq);
  float inv = 1.0f / fmaxf(sqrtf(ssq), 1e-12f);
  const float* a0 = augs + (size_t)b * D_DIM;    // augs[0][b]
  float dot = 0.f;
  #pragma unroll
  for (int i = 0; i < 3; ++i) {
    int k = tid + 256 * i;
    float nv = p[i] * inv;
    nn[(size_t)b * D_DIM + k] = nv;
    nnT[(size_t)k * B_ROWS + b] = nv;
    dot += nv * a0[k];
  }
  dot = block_sum(dot);
  if (tid == 0) num[b] = dot * 10.0f;            // 1/TEMP = 10
}

// ---- kernel 4: batch_den[j][b] += sum_i exp(10*dot(nn_b, aug_ji)) (double acc) ----
__global__ __launch_bounds__(256) void bden_kernel(const float* __restrict__ augs,
                                                   const float* __restrict__ nnT,
                                                   double* __restrict__ bden) {
  int jc = blockIdx.x;                 // 0..191
  int j = jc >> 6, c = jc & 63;
  int i0 = c * 4;
  __shared__ float s_aug[4 * D_DIM];
  const float* src = augs + ((size_t)j * B_ROWS + i0) * D_DIM;
  for (int idx = threadIdx.x; idx < 4 * D_DIM; idx += 256) s_aug[idx] = src[idx];
  __syncthreads();
  int b = threadIdx.x;
  float a0 = 0.f, a1 = 0.f, a2 = 0.f, a3 = 0.f;
  for (int k = 0; k < D_DIM; ++k) {
    float nv = nnT[(size_t)k * B_ROWS + b];
    a0 += nv * s_aug[k];
    a1 += nv * s_aug[D_DIM + k];
    a2 += nv * s_aug[2 * D_DIM + k];
    a3 += nv * s_aug[3 * D_DIM + k];
  }
  double v = exp((double)a0 * 10.0) + exp((double)a1 * 10.0) +
             exp((double)a2 * 10.0) + exp((double)a3 * 10.0);
  atomicAdd(&bden[j * B_ROWS + b], v);
}

// ---- kernel 5: GPS-filtered queue denominator (double exp-sum: e^277 is finite) ----
__global__ __launch_bounds__(256) void queue_kernel(const float* __restrict__ gps,
                                                    const float* __restrict__ sgps,
                                                    const float* __restrict__ sf,
                                                    const float* __restrict__ nn,
                                                    double* __restrict__ qden) {
  int b = blockIdx.x, tid = threadIdx.x;
  int w = tid >> 6, lane = tid & 63;
  __shared__ int qidx[QSZ];
  __shared__ int s_count;
  __shared__ int s_wcnt[4];
  __shared__ __align__(16) float s_nn[D_DIM];
  __shared__ double s_wsum[4];
  for (int k = tid; k < D_DIM; k += 256) s_nn[k] = nn[(size_t)b * D_DIM + k];
  if (tid == 0) s_count = 0;
  __syncthreads();

  const float r = 0.017453292519943295f;
  float lat1 = gps[b * 2 + 0] * r, lon1 = gps[b * 2 + 1] * r;
  float cl1 = cosf(lat1);
  int base = 0;
  while (true) {
    int count = s_count;
    if (count >= QSZ || base >= S_SUP) break;
    int s = base + tid;
    float lat2 = sgps[s * 2 + 0] * r, lon2 = sgps[s * 2 + 1] * r;
    float sdlat = sinf((lat2 - lat1) * 0.5f);
    float sdlon = sinf((lon2 - lon1) * 0.5f);
    float a = sdlat * sdlat + cl1 * cosf(lat2) * sdlon * sdlon;
    a = fminf(fmaxf(a, 0.f), 1.f);
    float d = 2.0f * 6371.0088f * asinf(sqrtf(a));
    bool valid = d > 25.0f;

    unsigned long long m = __ballot(valid);
    int wc = __popcll(m);
    if (lane == 0) s_wcnt[w] = wc;
    __syncthreads();
    int wbase = count;
    for (int i = 0; i < w; ++i) wbase += s_wcnt[i];
    int pos = wbase + __popcll(m & ((1ull << lane) - 1ull));
    if (valid && pos < QSZ) qidx[pos] = s;
    __syncthreads();
    if (tid == 0) {
      int total = s_wcnt[0] + s_wcnt[1] + s_wcnt[2] + s_wcnt[3];
      s_count = min(QSZ, count + total);
    }
    base += 256;
    __syncthreads();
  }
  int count = s_count;

  double acc = 0.0;
  const float4* nn4 = (const float4*)s_nn;
  for (int q = w; q < count; q += 4) {
    const float4* row = (const float4*)(sf + (size_t)qidx[q] * D_DIM);
    float dot = 0.f;
    #pragma unroll
    for (int i = 0; i < 3; ++i) {
      float4 a = row[lane + 64 * i];
      float4 nv = nn4[lane + 64 * i];
      dot += a.x * nv.x + a.y * nv.y + a.z * nv.z + a.w * nv.w;
    }
    #pragma unroll
    for (int m2 = 32; m2 >= 1; m2 >>= 1) dot += __shfl_xor(dot, m2, 64);
    acc += exp((double)dot * 10.0);     // double: dot can reach ~27.7 (self-hit)
  }
  if (lane == 0) s_wsum[w] = acc;
  __syncthreads();
  if (tid == 0)
    qden[b] = s_wsum[0] + s_wsum[1] + s_wsum[2] + s_wsum[3] + (double)(QSZ - count);
}

// ---- kernel 6: final scalar loss (double) ----
__global__ __launch_bounds__(256) void loss_kernel(const float* __restrict__ num,
                                                   const double* __restrict__ bden,
                                                   const double* __restrict__ qden,
                                                   float* __restrict__ out) {
  int b = threadIdx.x;
  double q = qden[b];
  double n = (double)num[b];
  double t = 0.0;
  #pragma unroll
  for (int j = 0; j < 3; ++j) t += n - log(bden[j * B_ROWS + b] + q);
  t = block_sum_d(t);
  if (b == 0) out[0] = (float)(-t / 256.0);
}

extern "C" void kernel_launch(void* const* d_in, const int* in_sizes, int n_in,
                              void* d_out, int out_size, void* d_ws, size_t ws_size,
                              hipStream_t stream) {
  const float* V    = (const float*)d_in[0];   // (4,256,768)
  const float* L    = (const float*)d_in[1];   // (256,768)
  const float* gps  = (const float*)d_in[2];   // (256,2)
  const float* sf   = (const float*)d_in[3];   // (65536,768)
  const float* sgps = (const float*)d_in[4];   // (65536,2)
  float* out = (float*)d_out;

  char* ws = (char*)d_ws;
  size_t off = 0;
  float* org  = (float*)(ws + off); off += 786432;        // 256*768*4
  float* augs = (float*)(ws + off); off += 2359296;       // 3*256*768*4
  float* nn   = (float*)(ws + off); off += 786432;
  float* nnT  = (float*)(ws + off); off += 786432;
  float* num  = (float*)(ws + off); off += 1024;          // 256*4
  double* bden = (double*)(ws + off); off += 6144;        // 3*256*8
  double* qden = (double*)(ws + off); off += 2048;        // 256*8
  unsigned long long* gmax = (unsigned long long*)(ws + off); off += 2048;

  init_kernel<<<1, 256, 0, stream>>>(gmax, bden);
  prep_kernel<<<1024, 256, 0, stream>>>(V, L, org, augs);
  sim_argmax_kernel<<<S_SUP / 64, 256, 0, stream>>>(org, sf, gmax);
  nn_kernel<<<B_ROWS, 256, 0, stream>>>(gmax, sf, augs, nn, nnT, num);
  bden_kernel<<<192, 256, 0, stream>>>(augs, nnT, bden);
  queue_kernel<<<B_ROWS, 256, 0, stream>>>(gps, sgps, sf, nn, qden);
  loss_kernel<<<1, 256, 0, stream>>>(num, bden, qden, out);
}

// Round 3
// 432.319 us; speedup vs baseline: 2.1407x; 2.1407x over previous
//
#include <hip/hip_runtime.h>
#include <hip/hip_bf16.h>

#define B_ROWS 256
#define S_SUP  65536
#define D_DIM  768
#define QSZ    512
#define NCHUNK 12          // 768 / 64
#define CHUNK_BYTES 32768  // 256 rows * 64 k * 2 B

typedef short bf16x8 __attribute__((ext_vector_type(8)));
typedef float f32x4  __attribute__((ext_vector_type(4)));

__device__ __forceinline__ bf16x8 cvt8(float4 a, float4 b) {
  bf16x8 r;
  r[0] = (short)(__float_as_uint(a.x) >> 16);
  r[1] = (short)(__float_as_uint(a.y) >> 16);
  r[2] = (short)(__float_as_uint(a.z) >> 16);
  r[3] = (short)(__float_as_uint(a.w) >> 16);
  r[4] = (short)(__float_as_uint(b.x) >> 16);
  r[5] = (short)(__float_as_uint(b.y) >> 16);
  r[6] = (short)(__float_as_uint(b.z) >> 16);
  r[7] = (short)(__float_as_uint(b.w) >> 16);
  return r;
}

__device__ __forceinline__ void gl_lds16(const void* g, void* l) {
  __builtin_amdgcn_global_load_lds(
      (const __attribute__((address_space(1))) unsigned int*)g,
      (__attribute__((address_space(3))) unsigned int*)l, 16, 0, 0);
}

// block-wide sum (float), result broadcast to all 256 threads (4 waves)
__device__ __forceinline__ float block_sum(float v) {
  __shared__ float tmp[4];
  #pragma unroll
  for (int m = 32; m >= 1; m >>= 1) v += __shfl_xor(v, m, 64);
  __syncthreads();
  if ((threadIdx.x & 63) == 0) tmp[threadIdx.x >> 6] = v;
  __syncthreads();
  return tmp[0] + tmp[1] + tmp[2] + tmp[3];
}

__device__ __forceinline__ double block_sum_d(double v) {
  __shared__ double tmp[4];
  #pragma unroll
  for (int m = 32; m >= 1; m >>= 1) v += __shfl_xor(v, m, 64);
  __syncthreads();
  if ((threadIdx.x & 63) == 0) tmp[threadIdx.x >> 6] = v;
  __syncthreads();
  return tmp[0] + tmp[1] + tmp[2] + tmp[3];
}

// ---- kernel 0: zero accumulators ----
__global__ __launch_bounds__(256) void init_kernel(unsigned long long* gmax, double* bden) {
  int t = threadIdx.x;
  gmax[t] = 0ull;
  for (int i = t; i < 3 * B_ROWS; i += 256) bden[i] = 0.0;
}

// ---- kernel 1: augs[j-1] = normalize(V[j]*L); j==0 -> org_bf16 (swizzled chunk image) ----
// org_bf16 layout: chunk c (k in [64c,64c+64)) is a 32 KB image: row r's 8 16B-groups,
// group jg stored at slot (jg ^ (r&7)).  ushort index = c*16384 + r*64 + slot*8 + e.
__global__ __launch_bounds__(256) void prep_kernel(const float* __restrict__ V,
                                                   const float* __restrict__ L,
                                                   unsigned short* __restrict__ orgb,
                                                   float* __restrict__ augs) {
  int jb = blockIdx.x;            // 0..1023
  int j = jb >> 8, b = jb & 255;
  int tid = threadIdx.x;
  const float* v = V + ((size_t)j * B_ROWS + b) * D_DIM;
  const float* l = L + (size_t)b * D_DIM;
  float p[3]; float ssq = 0.f;
  #pragma unroll
  for (int i = 0; i < 3; ++i) {
    int k = tid + 256 * i;
    p[i] = v[k] * l[k];
    ssq += p[i] * p[i];
  }
  ssq = block_sum(ssq);
  float inv = 1.0f / fmaxf(sqrtf(ssq), 1e-12f);
  if (j == 0) {
    #pragma unroll
    for (int i = 0; i < 3; ++i) {
      int k = tid + 256 * i;
      unsigned short hv = (unsigned short)(__float_as_uint(p[i] * inv) >> 16);
      int c = k >> 6, kk = k & 63, jg = kk >> 3, e = kk & 7;
      orgb[c * 16384 + b * 64 + ((jg ^ (b & 7)) << 3) + e] = hv;
    }
  } else {
    float* dst = augs + ((size_t)(j - 1) * B_ROWS + b) * D_DIM;
    #pragma unroll
    for (int i = 0; i < 3; ++i) dst[tid + 256 * i] = p[i] * inv;
  }
}

// ---- kernel 2: sim = org @ sf^T (bf16 MFMA, LDS-staged A), per-row argmax ----
__global__ __launch_bounds__(256) void sim_argmax_kernel(const unsigned short* __restrict__ orgb,
                                                         const float* __restrict__ sf,
                                                         unsigned long long* __restrict__ gmax) {
  const int tid  = threadIdx.x;
  const int w    = tid >> 6;          // wave 0..3
  const int lid  = tid & 63;
  const int quad = lid >> 4;          // 0..3
  const int r15  = lid & 15;          // 0..15
  const int s_col = blockIdx.x * 64 + w * 16 + r15;

  __shared__ __align__(16) char smem[CHUNK_BYTES];

  f32x4 acc[16];
  #pragma unroll
  for (int t = 0; t < 16; ++t) acc[t] = (f32x4){0.f, 0.f, 0.f, 0.f};

  const float* bp = sf + (size_t)s_col * D_DIM + quad * 8;
  const char* gsrc_base = (const char*)orgb;

  for (int c = 0; c < NCHUNK; ++c) {
    // stage chunk c: wave w copies bytes [w*8192, w*8192+8192) verbatim
    {
      const char* g = gsrc_base + c * CHUNK_BYTES + w * 8192 + lid * 16;
      char* ldst = smem + w * 8192;
      #pragma unroll
      for (int i = 0; i < 8; ++i)
        gl_lds16(g + i * 1024, ldst + i * 1024);
    }
    __syncthreads();

    #pragma unroll
    for (int k1 = 0; k1 < 2; ++k1) {
      int k0 = c * 64 + k1 * 32;
      float4 b0 = *(const float4*)(bp + k0);
      float4 b1 = *(const float4*)(bp + k0 + 4);
      bf16x8 bf = cvt8(b0, b1);
      // A from LDS: row r = r15+16t, group jg = k1*4+quad, slot = jg ^ (r15&7)
      int abase = r15 * 128 + (((k1 * 4 + quad) ^ (r15 & 7)) << 4);
      #pragma unroll
      for (int t = 0; t < 16; ++t) {
        bf16x8 af = *(const bf16x8*)(smem + abase + t * 2048);
        acc[t] = __builtin_amdgcn_mfma_f32_16x16x32_bf16(af, bf, acc[t], 0, 0, 0);
      }
    }
    __syncthreads();
  }

  __shared__ float smax[4 * 256];
  __shared__ int   sidx[4 * 256];
  #pragma unroll
  for (int t = 0; t < 16; ++t) {
    #pragma unroll
    for (int r = 0; r < 4; ++r) {
      float v = acc[t][r];
      int   idx = s_col;
      #pragma unroll
      for (int m = 1; m < 16; m <<= 1) {     // reduce over the 16 n-lanes
        float ov = __shfl_xor(v, m, 64);
        int   oi = __shfl_xor(idx, m, 64);
        if (ov > v || (ov == v && oi < idx)) { v = ov; idx = oi; }
      }
      if (r15 == 0) {
        int b = 16 * t + 4 * quad + r;       // C/D layout: row = quad*4+reg
        smax[w * 256 + b] = v;
        sidx[w * 256 + b] = idx;
      }
    }
  }
  __syncthreads();
  {
    int b = tid;
    float v = smax[b]; int idx = sidx[b];
    #pragma unroll
    for (int w2 = 1; w2 < 4; ++w2) {
      float ov = smax[w2 * 256 + b]; int oi = sidx[w2 * 256 + b];
      if (ov > v || (ov == v && oi < idx)) { v = ov; idx = oi; }
    }
    unsigned u = __float_as_uint(v);
    unsigned key = (u & 0x80000000u) ? ~u : (u | 0x80000000u);
    unsigned long long packed = ((unsigned long long)key << 32) |
                                (unsigned long long)(0xFFFFFFFFu - (unsigned)idx);
    atomicMax(gmax + b, packed);
  }
}

// ---- kernel 3: nn = normalize(sf[nn_idx]); nnT; num = dot(nn, augs[0][b]) / T ----
__global__ __launch_bounds__(256) void nn_kernel(const unsigned long long* __restrict__ gmax,
                                                 const float* __restrict__ sf,
                                                 const float* __restrict__ augs,
                                                 float* __restrict__ nn,
                                                 float* __restrict__ nnT,
                                                 float* __restrict__ num) {
  int b = blockIdx.x, tid = threadIdx.x;
  int idx = (int)(0xFFFFFFFFu - (unsigned)(gmax[b] & 0xFFFFFFFFull));
  const float* row = sf + (size_t)idx * D_DIM;
  float p[3]; float ssq = 0.f;
  #pragma unroll
  for (int i = 0; i < 3; ++i) { p[i] = row[tid + 256 * i]; ssq += p[i] * p[i]; }
  ssq = block_sum(ssq);
  float inv = 1.0f / fmaxf(sqrtf(ssq), 1e-12f);
  const float* a0 = augs + (size_t)b * D_DIM;    // augs[0][b]
  float dot = 0.f;
  #pragma unroll
  for (int i = 0; i < 3; ++i) {
    int k = tid + 256 * i;
    float nv = p[i] * inv;
    nn[(size_t)b * D_DIM + k] = nv;
    nnT[(size_t)k * B_ROWS + b] = nv;
    dot += nv * a0[k];
  }
  dot = block_sum(dot);
  if (tid == 0) num[b] = dot * 10.0f;            // 1/TEMP = 10
}

// ---- kernel 4: batch_den[j][b] += sum_i exp(10*dot(nn_b, aug_ji)) (double acc) ----
__global__ __launch_bounds__(256) void bden_kernel(const float* __restrict__ augs,
                                                   const float* __restrict__ nnT,
                                                   double* __restrict__ bden) {
  int jc = blockIdx.x;                 // 0..191
  int j = jc >> 6, c = jc & 63;
  int i0 = c * 4;
  __shared__ float s_aug[4 * D_DIM];
  const float* src = augs + ((size_t)j * B_ROWS + i0) * D_DIM;
  for (int idx = threadIdx.x; idx < 4 * D_DIM; idx += 256) s_aug[idx] = src[idx];
  __syncthreads();
  int b = threadIdx.x;
  float a0 = 0.f, a1 = 0.f, a2 = 0.f, a3 = 0.f;
  for (int k = 0; k < D_DIM; ++k) {
    float nv = nnT[(size_t)k * B_ROWS + b];
    a0 += nv * s_aug[k];
    a1 += nv * s_aug[D_DIM + k];
    a2 += nv * s_aug[2 * D_DIM + k];
    a3 += nv * s_aug[3 * D_DIM + k];
  }
  double v = exp((double)a0 * 10.0) + exp((double)a1 * 10.0) +
             exp((double)a2 * 10.0) + exp((double)a3 * 10.0);
  atomicAdd(&bden[j * B_ROWS + b], v);
}

// ---- kernel 5: GPS-filtered queue denominator (16 lanes per row, double exp-sum) ----
__global__ __launch_bounds__(256) void queue_kernel(const float* __restrict__ gps,
                                                    const float* __restrict__ sgps,
                                                    const float* __restrict__ sf,
                                                    const float* __restrict__ nn,
                                                    double* __restrict__ qden) {
  int b = blockIdx.x, tid = threadIdx.x;
  int w = tid >> 6, lane = tid & 63;
  __shared__ int qidx[QSZ];
  __shared__ int s_count;
  __shared__ int s_wcnt[4];
  __shared__ __align__(16) float s_nn[D_DIM];
  __shared__ double s_gsum[16];
  for (int k = tid; k < D_DIM; k += 256) s_nn[k] = nn[(size_t)b * D_DIM + k];
  if (tid == 0) s_count = 0;
  __syncthreads();

  const float r = 0.017453292519943295f;
  float lat1 = gps[b * 2 + 0] * r, lon1 = gps[b * 2 + 1] * r;
  float cl1 = cosf(lat1);
  int base = 0;
  while (true) {
    int count = s_count;
    if (count >= QSZ || base >= S_SUP) break;
    int s = base + tid;
    float lat2 = sgps[s * 2 + 0] * r, lon2 = sgps[s * 2 + 1] * r;
    float sdlat = sinf((lat2 - lat1) * 0.5f);
    float sdlon = sinf((lon2 - lon1) * 0.5f);
    float a = sdlat * sdlat + cl1 * cosf(lat2) * sdlon * sdlon;
    a = fminf(fmaxf(a, 0.f), 1.f);
    float d = 2.0f * 6371.0088f * asinf(sqrtf(a));
    bool valid = d > 25.0f;

    unsigned long long m = __ballot(valid);
    int wc = __popcll(m);
    if (lane == 0) s_wcnt[w] = wc;
    __syncthreads();
    int wbase = count;
    for (int i = 0; i < w; ++i) wbase += s_wcnt[i];
    int pos = wbase + __popcll(m & ((1ull << lane) - 1ull));
    if (valid && pos < QSZ) qidx[pos] = s;
    __syncthreads();
    if (tid == 0) {
      int total = s_wcnt[0] + s_wcnt[1] + s_wcnt[2] + s_wcnt[3];
      s_count = min(QSZ, count + total);
    }
    base += 256;
    __syncthreads();
  }
  int count = s_count;

  // phase 2: 16 lanes per row, 16 rows in flight per block
  int g  = lane >> 4;                  // group 0..3 within wave
  int l2 = lane & 15;
  double acc = 0.0;
  const float4* nn4 = (const float4*)s_nn;
  for (int q = w * 4 + g; q < count; q += 16) {
    const float4* row = (const float4*)(sf + (size_t)qidx[q] * D_DIM);
    float dot = 0.f;
    #pragma unroll
    for (int i = 0; i < 12; ++i) {
      float4 a = row[l2 + 16 * i];
      float4 nv = nn4[l2 + 16 * i];
      dot += a.x * nv.x + a.y * nv.y + a.z * nv.z + a.w * nv.w;
    }
    #pragma unroll
    for (int m2 = 8; m2 >= 1; m2 >>= 1) dot += __shfl_xor(dot, m2, 16);
    if (l2 == 0) acc += exp((double)dot * 10.0);
  }
  if (l2 == 0) s_gsum[w * 4 + g] = acc;
  __syncthreads();
  if (tid == 0) {
    double t = (double)(QSZ - count);
    #pragma unroll
    for (int i = 0; i < 16; ++i) t += s_gsum[i];
    qden[b] = t;
  }
}

// ---- kernel 6: final scalar loss (double) ----
__global__ __launch_bounds__(256) void loss_kernel(const float* __restrict__ num,
                                                   const double* __restrict__ bden,
                                                   const double* __restrict__ qden,
                                                   float* __restrict__ out) {
  int b = threadIdx.x;
  double q = qden[b];
  double n = (double)num[b];
  double t = 0.0;
  #pragma unroll
  for (int j = 0; j < 3; ++j) t += n - log(bden[j * B_ROWS + b] + q);
  t = block_sum_d(t);
  if (b == 0) out[0] = (float)(-t / 256.0);
}

extern "C" void kernel_launch(void* const* d_in, const int* in_sizes, int n_in,
                              void* d_out, int out_size, void* d_ws, size_t ws_size,
                              hipStream_t stream) {
  const float* V    = (const float*)d_in[0];   // (4,256,768)
  const float* L    = (const float*)d_in[1];   // (256,768)
  const float* gps  = (const float*)d_in[2];   // (256,2)
  const float* sf   = (const float*)d_in[3];   // (65536,768)
  const float* sgps = (const float*)d_in[4];   // (65536,2)
  float* out = (float*)d_out;

  char* ws = (char*)d_ws;
  size_t off = 0;
  unsigned short* orgb = (unsigned short*)(ws + off); off += 393216;  // 12*32KB bf16 swizzled
  float* augs = (float*)(ws + off); off += 2359296;                   // 3*256*768*4
  float* nn   = (float*)(ws + off); off += 786432;
  float* nnT  = (float*)(ws + off); off += 786432;
  float* num  = (float*)(ws + off); off += 1024;                      // 256*4
  double* bden = (double*)(ws + off); off += 6144;                    // 3*256*8
  double* qden = (double*)(ws + off); off += 2048;                    // 256*8
  unsigned long long* gmax = (unsigned long long*)(ws + off); off += 2048;

  init_kernel<<<1, 256, 0, stream>>>(gmax, bden);
  prep_kernel<<<1024, 256, 0, stream>>>(V, L, orgb, augs);
  sim_argmax_kernel<<<S_SUP / 64, 256, 0, stream>>>(orgb, sf, gmax);
  nn_kernel<<<B_ROWS, 256, 0, stream>>>(gmax, sf, augs, nn, nnT, num);
  bden_kernel<<<192, 256, 0, stream>>>(augs, nnT, bden);
  queue_kernel<<<B_ROWS, 256, 0, stream>>>(gps, sgps, sf, nn, qden);
  loss_kernel<<<1, 256, 0, stream>>>(num, bden, qden, out);
}